// Round 6
// baseline (207.698 us; speedup 1.0000x reference)
//
#include <hip/hip_runtime.h>

typedef __attribute__((ext_vector_type(8))) __bf16 bf16x8;
typedef __attribute__((ext_vector_type(8))) _Float16 f16x8;
typedef __attribute__((ext_vector_type(4))) float f32x4;
typedef __attribute__((ext_vector_type(8))) unsigned short u16x8;

#define MFMA_BF16(a, b, c) __builtin_amdgcn_mfma_f32_16x16x32_bf16((a), (b), (c), 0, 0, 0)
#define MFMA_F16(a, b, c)  __builtin_amdgcn_mfma_f32_16x16x32_f16((a), (b), (c), 0, 0, 0)
#define LOG2E 1.44269504088896340736f

__device__ __forceinline__ float b2f(unsigned short u) {
    union { unsigned int i; float f; } v; v.i = ((unsigned int)u) << 16; return v.f;
}
__device__ __forceinline__ unsigned short f2bf(float f) {
    union { float f; unsigned int i; } v; v.f = f;
    unsigned int u = v.i;
    return (unsigned short)((u + 0x7fffu + ((u >> 16) & 1u)) >> 16);
}

// async global->LDS, 16B/lane. HW dest = wave-uniform base + lane*16 (m104).
// Swizzle is applied on the GLOBAL side so conflict-free LDS layouts coexist with it.
__device__ __forceinline__ void gl_lds16(const void* g, void* l) {
    __builtin_amdgcn_global_load_lds(
        (const __attribute__((address_space(1))) void*)g,
        (__attribute__((address_space(3))) void*)l,
        16, 0, 0);
}

// ---------------- fp32 -> bf16 conversion of all 5 inputs (one launch) ------------
__global__ __launch_bounds__(256) void cvt_all(const float* __restrict__ x,
                                               const float* __restrict__ wq,
                                               const float* __restrict__ wk,
                                               const float* __restrict__ wv,
                                               const float* __restrict__ wo,
                                               unsigned short* __restrict__ xb,
                                               unsigned short* __restrict__ wqb,
                                               unsigned short* __restrict__ wkb,
                                               unsigned short* __restrict__ wvb,
                                               unsigned short* __restrict__ wob) {
    int id = blockIdx.x * 256 + threadIdx.x;  // [0, 1M)
    const float* src; unsigned short* dst; size_t off;
    if (id < 524288)      { src = x;  dst = xb;  off = (size_t)id * 8; }
    else if (id < 655360) { src = wq; dst = wqb; off = (size_t)(id - 524288) * 8; }
    else if (id < 786432) { src = wk; dst = wkb; off = (size_t)(id - 655360) * 8; }
    else if (id < 917504) { src = wv; dst = wvb; off = (size_t)(id - 786432) * 8; }
    else                  { src = wo; dst = wob; off = (size_t)(id - 917504) * 8; }
    float4 a = *(const float4*)(src + off);
    float4 b = *(const float4*)(src + off + 4);
    u16x8 o;
    o[0] = f2bf(a.x); o[1] = f2bf(a.y); o[2] = f2bf(a.z); o[3] = f2bf(a.w);
    o[4] = f2bf(b.x); o[5] = f2bf(b.y); o[6] = f2bf(b.z); o[7] = f2bf(b.w);
    *(u16x8*)(dst + off) = o;
}

// ---------------- GEMM core: C[MxN] = A[MxK]*B[NxK]^T, bf16 in, fp32 accum --------
// 128x128 tile, BK=32, K=1024 fixed, A/B row stride 1024. LDS chunk (r,cpos) holds
// source chunk cpos^((r>>1)&3) -> frag ds_read_b128 is 2-way (free).
// MODE: 0 = bf16 out, 1 = f32 out, 2 = f16 out. ldc runtime.
template <int MODE>
__device__ __forceinline__ void gemm128_bt(const unsigned short* __restrict__ A,
                                           const unsigned short* __restrict__ B,
                                           void* __restrict__ Cv,
                                           int m0, int n0, int ldc,
                                           unsigned short* As, unsigned short* Bs) {
    const int tid = threadIdx.x;
    const int w = tid >> 6, lane = tid & 63;
    const int quad = lane >> 4, l15 = lane & 15;
    const int wm = w & 1, wn = w >> 1;

    f32x4 acc[4][4];
#pragma unroll
    for (int mt = 0; mt < 4; ++mt)
#pragma unroll
        for (int nt = 0; nt < 4; ++nt) acc[mt][nt] = f32x4{0.f, 0.f, 0.f, 0.f};

    for (int k0 = 0; k0 < 1024; k0 += 32) {
        __syncthreads();
#pragma unroll
        for (int i = 0; i < 2; ++i) {
            int L = (w * 2 + i) * 64 + lane;      // chunk index in tile
            int r = L >> 2;
            int c = (L & 3) ^ ((r >> 1) & 3);     // swizzled source chunk
            gl_lds16(A + (size_t)(m0 + r) * 1024 + k0 + c * 8, As + L * 8);
            gl_lds16(B + (size_t)(n0 + r) * 1024 + k0 + c * 8, Bs + L * 8);
        }
        __syncthreads();

        bf16x8 af[4], bfr[4];
#pragma unroll
        for (int mt = 0; mt < 4; ++mt) {
            int row = wm * 64 + mt * 16 + l15;
            af[mt] = *(const bf16x8*)(As + row * 32 + (quad ^ ((row >> 1) & 3)) * 8);
        }
#pragma unroll
        for (int nt = 0; nt < 4; ++nt) {
            int row = wn * 64 + nt * 16 + l15;
            bfr[nt] = *(const bf16x8*)(Bs + row * 32 + (quad ^ ((row >> 1) & 3)) * 8);
        }
#pragma unroll
        for (int mt = 0; mt < 4; ++mt)
#pragma unroll
            for (int nt = 0; nt < 4; ++nt)
                acc[mt][nt] = MFMA_BF16(af[mt], bfr[nt], acc[mt][nt]);
    }

#pragma unroll
    for (int mt = 0; mt < 4; ++mt) {
        int grow = m0 + wm * 64 + mt * 16 + quad * 4;
#pragma unroll
        for (int nt = 0; nt < 4; ++nt) {
            int gcol = n0 + wn * 64 + nt * 16 + l15;
#pragma unroll
            for (int r = 0; r < 4; ++r) {
                float val = acc[mt][nt][r];
                size_t idx = (size_t)(grow + r) * ldc + gcol;
                if constexpr (MODE == 0) {
                    ((unsigned short*)Cv)[idx] = f2bf(val);
                } else if constexpr (MODE == 1) {
                    ((float*)Cv)[idx] = val;
                } else {
                    _Float16 hv = (_Float16)val;
                    ((unsigned short*)Cv)[idx] = __builtin_bit_cast(unsigned short, hv);
                }
            }
        }
    }
}

// Q/K: C[token][ch] bf16 (ldc 1024). V: C = Wv * X^T = V^T[ch][token] f16 (ldc 4096).
__global__ __launch_bounds__(256) void gemm_qkv(const unsigned short* __restrict__ X,
                                                const unsigned short* __restrict__ Wq,
                                                const unsigned short* __restrict__ Wk,
                                                const unsigned short* __restrict__ Wv,
                                                unsigned short* __restrict__ Qo,
                                                unsigned short* __restrict__ Ko,
                                                unsigned short* __restrict__ Vt) {
    __shared__ unsigned short As[128 * 32];
    __shared__ unsigned short Bs[128 * 32];
    int y = blockIdx.y;
    if (y < 16) {
        int sel = y >> 3;
        int m0 = blockIdx.x * 128;         // tokens
        int n0 = (y & 7) * 128;            // channels
        const unsigned short* B = sel ? Wk : Wq;
        unsigned short* C = sel ? Ko : Qo;
        gemm128_bt<0>(X, B, C, m0, n0, 1024, As, Bs);
    } else {
        int m0 = (y & 7) * 128;            // channels
        int n0 = blockIdx.x * 128;         // tokens
        gemm128_bt<2>(Wv, X, Vt, m0, n0, 4096, As, Bs);
    }
}

__global__ __launch_bounds__(256) void gemm_out(const unsigned short* __restrict__ A,
                                                const unsigned short* __restrict__ Wo,
                                                float* __restrict__ C) {
    __shared__ unsigned short As[128 * 32];
    __shared__ unsigned short Bs[128 * 32];
    gemm128_bt<1>(A, Wo, C, blockIdx.x * 128, blockIdx.y * 128, 1024, As, Bs);
}

// ---------------- RoPE in-place; Q gets 0.125*log2(e) folded in (M=0 softmax) -----
__global__ __launch_bounds__(256) void rope_qk(unsigned short* __restrict__ Q,
                                               unsigned short* __restrict__ K) {
    int id = blockIdx.x * 256 + threadIdx.x;   // 0 .. 2*4096*512-1
    int tsel = id >> 21;
    int rgt = id & 0x1FFFFF;
    int row = rgt >> 9;
    int p = rgt & 511;
    int pp = p & 31;
    int col = (p >> 5) * 64 + pp * 2;
    float pos = (float)(row & 2047);
    float inv_freq = exp2f(-0.41524101186092029f * (float)pp);
    float ang = pos * inv_freq;
    float sn, cs;
    sincosf(ang, &sn, &cs);
    unsigned short* buf = tsel ? K : Q;
    float scale = tsel ? 1.0f : (0.125f * LOG2E);
    size_t base = (size_t)row * 1024 + col;
    float xe = b2f(buf[base]), xo = b2f(buf[base + 1]);
    buf[base]     = f2bf((xe * cs - xo * sn) * scale);
    buf[base + 1] = f2bf((xe * sn + xo * cs) * scale);
}

// ---------------- Flash attention, S^T orientation, 32 q-rows/wave -----------------
// S^T = K*Q^T: K/V fragments are q-independent (A-operands) -> one LDS read set
// feeds both 16-q halves. P stored [q][key] (stride 72): packed b64 writes,
// contiguous b128 B-frag reads. O^T = V^T * P^T. Mask peeled to diagonal block.
// grid 512 XCD-swizzled; block = 128 q-rows (4 waves x 32q); dbuf K/V staging.
#define FBODY(KB, MASKED)                                                               \
    {                                                                                   \
        const int kb_ = (KB);                                                           \
        const unsigned short* Kc = Ks[kb_ & 1];                                         \
        const unsigned short* Vc = Vs[kb_ & 1];                                         \
        bf16x8 kf[4][2];                                                                \
        f16x8 vf[4][2];                                                                 \
        _Pragma("unroll")                                                               \
        for (int t = 0; t < 4; ++t) {                                                   \
            int row = t * 16 + l15;                                                     \
            int cof = (quad ^ (row & 7)) * 8;                                           \
            kf[t][0] = *(const bf16x8*)(Kc + row * 64 + cof);                           \
            kf[t][1] = *(const bf16x8*)(Kc + row * 64 + (cof ^ 32));                    \
            vf[t][0] = *(const f16x8*)(Vc + row * 64 + cof);                            \
            vf[t][1] = *(const f16x8*)(Vc + row * 64 + (cof ^ 32));                     \
        }                                                                               \
        _Pragma("unroll")                                                               \
        for (int hf = 0; hf < 2; ++hf) {                                                \
            f32x4 s[4];                                                                 \
            _Pragma("unroll")                                                           \
            for (int nt = 0; nt < 4; ++nt) {                                            \
                f32x4 z = f32x4{0.f, 0.f, 0.f, 0.f};                                    \
                s[nt] = MFMA_BF16(kf[nt][0], qf[hf][0], z);                             \
                s[nt] = MFMA_BF16(kf[nt][1], qf[hf][1], s[nt]);                         \
            }                                                                           \
            unsigned short* Pw = Ps[w][hf];                                             \
            _Pragma("unroll")                                                           \
            for (int nt = 0; nt < 4; ++nt) {                                            \
                float e[4];                                                             \
                _Pragma("unroll")                                                       \
                for (int r = 0; r < 4; ++r) {                                           \
                    float ev = exp2f(s[nt][r]);                                         \
                    if (MASKED) {                                                       \
                        int kpos = kb_ * 64 + nt * 16 + quad * 4 + r;                   \
                        int qpos = qpos0 + hf * 16 + l15;                               \
                        ev = (kpos > qpos) ? 0.f : ev;                                  \
                    }                                                                   \
                    e[r] = ev;                                                          \
                }                                                                       \
                uint2 pk;                                                               \
                pk.x = __builtin_bit_cast(unsigned,                                     \
                           __builtin_amdgcn_cvt_pkrtz(e[0], e[1]));                     \
                pk.y = __builtin_bit_cast(unsigned,                                     \
                           __builtin_amdgcn_cvt_pkrtz(e[2], e[3]));                     \
                *(uint2*)(Pw + l15 * 72 + nt * 16 + quad * 4) = pk;                     \
            }                                                                           \
        }                                                                               \
        __asm__ volatile("s_waitcnt lgkmcnt(0)" ::: "memory");                          \
        _Pragma("unroll")                                                               \
        for (int hf = 0; hf < 2; ++hf) {                                                \
            const unsigned short* Pw = Ps[w][hf];                                       \
            f16x8 pf0 = *(const f16x8*)(Pw + l15 * 72 + quad * 8);                      \
            f16x8 pf1 = *(const f16x8*)(Pw + l15 * 72 + 32 + quad * 8);                 \
            lacc[hf] = MFMA_F16(ones, pf0, lacc[hf]);                                   \
            lacc[hf] = MFMA_F16(ones, pf1, lacc[hf]);                                   \
            _Pragma("unroll")                                                           \
            for (int dt = 0; dt < 4; ++dt) {                                            \
                accO[hf][dt] = MFMA_F16(vf[dt][0], pf0, accO[hf][dt]);                  \
                accO[hf][dt] = MFMA_F16(vf[dt][1], pf1, accO[hf][dt]);                  \
            }                                                                           \
        }                                                                               \
    }

__global__ __launch_bounds__(256, 3) void flash_attn(const unsigned short* __restrict__ Q,
                                                     const unsigned short* __restrict__ Kb,
                                                     const unsigned short* __restrict__ Vt,
                                                     unsigned short* __restrict__ O) {
    int id = blockIdx.x;
    int xcd = id & 7, rem = id >> 3;
    int qt = 15 - (rem & 15);          // 128-row q-tiles, largest first per XCD
    int bh = xcd + 8 * (rem >> 4);
    int b = bh >> 4, h = bh & 15;
    int tid = threadIdx.x, w = tid >> 6, lane = tid & 63;
    int quad = lane >> 4, l15 = lane & 15;
    int qbase = b * 2048 + qt * 128 + w * 32;   // global token row base (wave)
    int qpos0 = qt * 128 + w * 32;              // sequence position base (wave)
    int last_w = qpos0 >> 6;                    // wave's diagonal key-block
    int nkbB = 2 * qt + 2;                      // key blocks staged by the block

    __shared__ unsigned short Ks[2][64 * 64];   // bf16 [key][d], chunk-swizzled
    __shared__ unsigned short Vs[2][64 * 64];   // f16  [d][key], chunk-swizzled
    __shared__ unsigned short Ps[4][2][16 * 72];// f16 P^T scratch [q][key], stride 72

    bf16x8 qf[2][2];
#pragma unroll
    for (int hf = 0; hf < 2; ++hf) {
        const unsigned short* qp =
            Q + (size_t)(qbase + hf * 16 + l15) * 1024 + h * 64 + quad * 8;
        qf[hf][0] = *(const bf16x8*)qp;
        qf[hf][1] = *(const bf16x8*)(qp + 32);
    }
    f16x8 ones;
#pragma unroll
    for (int j = 0; j < 8; ++j) ones[j] = (_Float16)1.0f;

    // staging: chunk L=(w*2+i)*64+lane; row r=L>>3, lds col cpos=L&7 holds src cpos^(r&7)
    int L0 = w * 128 + lane;
    int L1 = L0 + 64;
    int r0 = L0 >> 3, c0s = (L0 & 7) ^ (r0 & 7);
    int r1 = L1 >> 3, c1s = (L1 & 7) ^ (r1 & 7);
    const unsigned short* Kg0 = Kb + (size_t)(b * 2048 + r0) * 1024 + h * 64 + c0s * 8;
    const unsigned short* Kg1 = Kb + (size_t)(b * 2048 + r1) * 1024 + h * 64 + c1s * 8;
    const unsigned short* Vg0 = Vt + (size_t)(h * 64 + r0) * 4096 + b * 2048 + c0s * 8;
    const unsigned short* Vg1 = Vt + (size_t)(h * 64 + r1) * 4096 + b * 2048 + c1s * 8;

    f32x4 accO[2][4];
#pragma unroll
    for (int hf = 0; hf < 2; ++hf)
#pragma unroll
        for (int dt = 0; dt < 4; ++dt) accO[hf][dt] = f32x4{0.f, 0.f, 0.f, 0.f};
    f32x4 lacc[2] = {f32x4{0.f, 0.f, 0.f, 0.f}, f32x4{0.f, 0.f, 0.f, 0.f}};

    // prologue: stage key-block 0 into buf 0
    gl_lds16(Kg0, Ks[0] + L0 * 8);
    gl_lds16(Kg1, Ks[0] + L1 * 8);
    gl_lds16(Vg0, Vs[0] + L0 * 8);
    gl_lds16(Vg1, Vs[0] + L1 * 8);

    for (int kb = 0; kb < nkbB; ++kb) {
        __syncthreads();                    // drains stage(kb), then barrier
        if (kb + 1 < nkbB) {
            int bi = (kb + 1) & 1;
            size_t ko = (size_t)(kb + 1) * 64 * 1024;
            size_t vo = (size_t)(kb + 1) * 64;
            gl_lds16(Kg0 + ko, Ks[bi] + L0 * 8);
            gl_lds16(Kg1 + ko, Ks[bi] + L1 * 8);
            gl_lds16(Vg0 + vo, Vs[bi] + L0 * 8);
            gl_lds16(Vg1 + vo, Vs[bi] + L1 * 8);
        }
        if (kb < last_w) {
            FBODY(kb, 0)
        } else if (kb == last_w) {
            FBODY(kb, 1)
        }
    }

    // ---- epilogue: O = O^T / rowsum; pack 4 consecutive ch into dwordx2 ----
#pragma unroll
    for (int hf = 0; hf < 2; ++hf) {
        float inv = 1.0f / lacc[hf][0];     // all regs/quads identical (ones-MFMA)
        int tok = qbase + hf * 16 + l15;
#pragma unroll
        for (int dt = 0; dt < 4; ++dt) {
            uint2 pk;
            pk.x = (unsigned)f2bf(accO[hf][dt][0] * inv) |
                   ((unsigned)f2bf(accO[hf][dt][1] * inv) << 16);
            pk.y = (unsigned)f2bf(accO[hf][dt][2] * inv) |
                   ((unsigned)f2bf(accO[hf][dt][3] * inv) << 16);
            *(uint2*)(O + (size_t)tok * 1024 + h * 64 + dt * 16 + quad * 4) = pk;
        }
    }
}

extern "C" void kernel_launch(void* const* d_in, const int* in_sizes, int n_in,
                              void* d_out, int out_size, void* d_ws, size_t ws_size,
                              hipStream_t stream) {
    (void)in_sizes; (void)n_in; (void)out_size; (void)ws_size;
    const float* x  = (const float*)d_in[0];
    const float* wq = (const float*)d_in[1];
    const float* wk = (const float*)d_in[2];
    const float* wv = (const float*)d_in[3];
    const float* wo = (const float*)d_in[4];
    float* out = (float*)d_out;

    const size_t T = (size_t)4096 * 1024;
    const size_t W = (size_t)1024 * 1024;
    unsigned short* Q   = (unsigned short*)d_ws;
    unsigned short* K   = Q + T;
    unsigned short* Vt  = K + T;      // f16 [ch][token], ldc 4096
    unsigned short* AO  = Vt + T;
    unsigned short* xb  = AO + T;
    unsigned short* wqb = xb + T;
    unsigned short* wkb = wqb + W;
    unsigned short* wvb = wkb + W;
    unsigned short* wob = wvb + W;

    cvt_all  <<<dim3(4096),   256, 0, stream>>>(x, wq, wk, wv, wo, xb, wqb, wkb, wvb, wob);
    gemm_qkv <<<dim3(32, 24), 256, 0, stream>>>(xb, wqb, wkb, wvb, Q, K, Vt);
    rope_qk  <<<dim3(16384),  256, 0, stream>>>(Q, K);
    flash_attn<<<dim3(512),   256, 0, stream>>>(Q, K, Vt, AO);
    gemm_out <<<dim3(32, 8),  256, 0, stream>>>(AO, wob, out);
}

// Round 7
// 199.085 us; speedup vs baseline: 1.0433x; 1.0433x over previous
//
#include <hip/hip_runtime.h>

typedef __attribute__((ext_vector_type(8))) __bf16 bf16x8;
typedef __attribute__((ext_vector_type(8))) _Float16 f16x8;
typedef __attribute__((ext_vector_type(4))) float f32x4;
typedef __attribute__((ext_vector_type(8))) unsigned short u16x8;

#define MFMA_BF16(a, b, c) __builtin_amdgcn_mfma_f32_16x16x32_bf16((a), (b), (c), 0, 0, 0)
#define MFMA_F16(a, b, c)  __builtin_amdgcn_mfma_f32_16x16x32_f16((a), (b), (c), 0, 0, 0)
#define LOG2E 1.44269504088896340736f

__device__ __forceinline__ float b2f(unsigned short u) {
    union { unsigned int i; float f; } v; v.i = ((unsigned int)u) << 16; return v.f;
}
__device__ __forceinline__ unsigned short f2bf(float f) {
    union { float f; unsigned int i; } v; v.f = f;
    unsigned int u = v.i;
    return (unsigned short)((u + 0x7fffu + ((u >> 16) & 1u)) >> 16);
}

// async global->LDS, 16B/lane. HW dest = wave-uniform base + lane*16 (m104).
// Swizzle is applied on the GLOBAL side so conflict-free LDS layouts coexist with it.
__device__ __forceinline__ void gl_lds16(const void* g, void* l) {
    __builtin_amdgcn_global_load_lds(
        (const __attribute__((address_space(1))) void*)g,
        (__attribute__((address_space(3))) void*)l,
        16, 0, 0);
}

// ---------------- fp32 -> bf16 conversion of all 5 inputs (one launch) ------------
__global__ __launch_bounds__(256) void cvt_all(const float* __restrict__ x,
                                               const float* __restrict__ wq,
                                               const float* __restrict__ wk,
                                               const float* __restrict__ wv,
                                               const float* __restrict__ wo,
                                               unsigned short* __restrict__ xb,
                                               unsigned short* __restrict__ wqb,
                                               unsigned short* __restrict__ wkb,
                                               unsigned short* __restrict__ wvb,
                                               unsigned short* __restrict__ wob) {
    int id = blockIdx.x * 256 + threadIdx.x;  // [0, 1M)
    const float* src; unsigned short* dst; size_t off;
    if (id < 524288)      { src = x;  dst = xb;  off = (size_t)id * 8; }
    else if (id < 655360) { src = wq; dst = wqb; off = (size_t)(id - 524288) * 8; }
    else if (id < 786432) { src = wk; dst = wkb; off = (size_t)(id - 655360) * 8; }
    else if (id < 917504) { src = wv; dst = wvb; off = (size_t)(id - 786432) * 8; }
    else                  { src = wo; dst = wob; off = (size_t)(id - 917504) * 8; }
    float4 a = *(const float4*)(src + off);
    float4 b = *(const float4*)(src + off + 4);
    u16x8 o;
    o[0] = f2bf(a.x); o[1] = f2bf(a.y); o[2] = f2bf(a.z); o[3] = f2bf(a.w);
    o[4] = f2bf(b.x); o[5] = f2bf(b.y); o[6] = f2bf(b.z); o[7] = f2bf(b.w);
    *(u16x8*)(dst + off) = o;
}

// ---------------- GEMM core: C[MxN] = A[MxK]*B[NxK]^T, bf16 in, fp32 accum --------
// 128x128 tile, BK=32, K=1024 fixed, A/B row stride 1024. LDS chunk (r,cpos) holds
// source chunk cpos^((r>>1)&3) -> frag ds_read_b128 is 2-way (free).
// MODE: 0 = bf16 out, 1 = f32 out, 2 = f16 out. ldc runtime.
template <int MODE>
__device__ __forceinline__ void gemm128_bt(const unsigned short* __restrict__ A,
                                           const unsigned short* __restrict__ B,
                                           void* __restrict__ Cv,
                                           int m0, int n0, int ldc,
                                           unsigned short* As, unsigned short* Bs) {
    const int tid = threadIdx.x;
    const int w = tid >> 6, lane = tid & 63;
    const int quad = lane >> 4, l15 = lane & 15;
    const int wm = w & 1, wn = w >> 1;

    f32x4 acc[4][4];
#pragma unroll
    for (int mt = 0; mt < 4; ++mt)
#pragma unroll
        for (int nt = 0; nt < 4; ++nt) acc[mt][nt] = f32x4{0.f, 0.f, 0.f, 0.f};

    for (int k0 = 0; k0 < 1024; k0 += 32) {
        __syncthreads();
#pragma unroll
        for (int i = 0; i < 2; ++i) {
            int L = (w * 2 + i) * 64 + lane;      // chunk index in tile
            int r = L >> 2;
            int c = (L & 3) ^ ((r >> 1) & 3);     // swizzled source chunk
            gl_lds16(A + (size_t)(m0 + r) * 1024 + k0 + c * 8, As + L * 8);
            gl_lds16(B + (size_t)(n0 + r) * 1024 + k0 + c * 8, Bs + L * 8);
        }
        __syncthreads();

        bf16x8 af[4], bfr[4];
#pragma unroll
        for (int mt = 0; mt < 4; ++mt) {
            int row = wm * 64 + mt * 16 + l15;
            af[mt] = *(const bf16x8*)(As + row * 32 + (quad ^ ((row >> 1) & 3)) * 8);
        }
#pragma unroll
        for (int nt = 0; nt < 4; ++nt) {
            int row = wn * 64 + nt * 16 + l15;
            bfr[nt] = *(const bf16x8*)(Bs + row * 32 + (quad ^ ((row >> 1) & 3)) * 8);
        }
#pragma unroll
        for (int mt = 0; mt < 4; ++mt)
#pragma unroll
            for (int nt = 0; nt < 4; ++nt)
                acc[mt][nt] = MFMA_BF16(af[mt], bfr[nt], acc[mt][nt]);
    }

#pragma unroll
    for (int mt = 0; mt < 4; ++mt) {
        int grow = m0 + wm * 64 + mt * 16 + quad * 4;
#pragma unroll
        for (int nt = 0; nt < 4; ++nt) {
            int gcol = n0 + wn * 64 + nt * 16 + l15;
#pragma unroll
            for (int r = 0; r < 4; ++r) {
                float val = acc[mt][nt][r];
                size_t idx = (size_t)(grow + r) * ldc + gcol;
                if constexpr (MODE == 0) {
                    ((unsigned short*)Cv)[idx] = f2bf(val);
                } else if constexpr (MODE == 1) {
                    ((float*)Cv)[idx] = val;
                } else {
                    _Float16 hv = (_Float16)val;
                    ((unsigned short*)Cv)[idx] = __builtin_bit_cast(unsigned short, hv);
                }
            }
        }
    }
}

// Q/K: C[token][ch] bf16 (ldc 1024). V: C = Wv * X^T = V^T[ch][token] f16 (ldc 4096).
__global__ __launch_bounds__(256) void gemm_qkv(const unsigned short* __restrict__ X,
                                                const unsigned short* __restrict__ Wq,
                                                const unsigned short* __restrict__ Wk,
                                                const unsigned short* __restrict__ Wv,
                                                unsigned short* __restrict__ Qo,
                                                unsigned short* __restrict__ Ko,
                                                unsigned short* __restrict__ Vt) {
    __shared__ unsigned short As[128 * 32];
    __shared__ unsigned short Bs[128 * 32];
    int y = blockIdx.y;
    if (y < 16) {
        int sel = y >> 3;
        int m0 = blockIdx.x * 128;         // tokens
        int n0 = (y & 7) * 128;            // channels
        const unsigned short* B = sel ? Wk : Wq;
        unsigned short* C = sel ? Ko : Qo;
        gemm128_bt<0>(X, B, C, m0, n0, 1024, As, Bs);
    } else {
        int m0 = (y & 7) * 128;            // channels
        int n0 = blockIdx.x * 128;         // tokens
        gemm128_bt<2>(Wv, X, Vt, m0, n0, 4096, As, Bs);
    }
}

__global__ __launch_bounds__(256) void gemm_out(const unsigned short* __restrict__ A,
                                                const unsigned short* __restrict__ Wo,
                                                float* __restrict__ C) {
    __shared__ unsigned short As[128 * 32];
    __shared__ unsigned short Bs[128 * 32];
    gemm128_bt<1>(A, Wo, C, blockIdx.x * 128, blockIdx.y * 128, 1024, As, Bs);
}

// ---------------- RoPE in-place; Q gets 0.125*log2(e) folded in (M=0 softmax) -----
// native __sinf/__cosf: arg <= 2047 rad -> phase err ~2e-4 rad << bf16 ulp.
__global__ __launch_bounds__(256) void rope_qk(unsigned short* __restrict__ Q,
                                               unsigned short* __restrict__ K) {
    int id = blockIdx.x * 256 + threadIdx.x;   // 0 .. 2*4096*512-1
    int tsel = id >> 21;
    int rgt = id & 0x1FFFFF;
    int row = rgt >> 9;
    int p = rgt & 511;
    int pp = p & 31;
    int col = (p >> 5) * 64 + pp * 2;
    float pos = (float)(row & 2047);
    float inv_freq = exp2f(-0.41524101186092029f * (float)pp);
    float ang = pos * inv_freq;
    float sn = __sinf(ang);
    float cs = __cosf(ang);
    unsigned short* buf = tsel ? K : Q;
    float scale = tsel ? 1.0f : (0.125f * LOG2E);
    size_t base = (size_t)row * 1024 + col;
    float xe = b2f(buf[base]), xo = b2f(buf[base + 1]);
    buf[base]     = f2bf((xe * cs - xo * sn) * scale);
    buf[base + 1] = f2bf((xe * sn + xo * cs) * scale);
}

// ---------------- Flash attention, causal, M=0, double-buffered K/V ----------------
// Round-5 structure (64q block, 16q/wave, 3 blocks/CU) + WORK-BALANCED schedule:
// CU slot j gets qt in {j, 31-j, (j+16)&31, 31-((j+16)&31)} -> sum(qt+1)=66 per CU
// (the old largest-first map gave CU j four identical qt=31-j -> makespan 128 vs 66).
// Mask peeled to the diagonal key-block only.
#define FBODY(KB, MASKED)                                                               \
    {                                                                                   \
        const int kb_ = (KB);                                                           \
        const unsigned short* Kc = Ks[kb_ & 1];                                         \
        const unsigned short* Vc = Vs[kb_ & 1];                                         \
        f32x4 sc[4];                                                                    \
        _Pragma("unroll")                                                               \
        for (int nt = 0; nt < 4; ++nt) {                                                \
            int row = nt * 16 + l15;                                                    \
            int cof = (quad ^ (row & 7)) * 8;                                           \
            bf16x8 kf0 = *(const bf16x8*)(Kc + row * 64 + cof);                         \
            bf16x8 kf1 = *(const bf16x8*)(Kc + row * 64 + (cof ^ 32));                  \
            f32x4 z = f32x4{0.f, 0.f, 0.f, 0.f};                                        \
            sc[nt] = MFMA_BF16(qf0, kf0, z);                                            \
            sc[nt] = MFMA_BF16(qf1, kf1, sc[nt]);                                       \
        }                                                                               \
        unsigned short* Pw = Ps[w];                                                     \
        _Pragma("unroll")                                                               \
        for (int nt = 0; nt < 4; ++nt) {                                                \
            float e[4];                                                                 \
            _Pragma("unroll")                                                           \
            for (int r = 0; r < 4; ++r) {                                               \
                float ev = exp2f(sc[nt][r]);                                            \
                if (MASKED) {                                                           \
                    int kpos = kb_ * 64 + nt * 16 + l15;                                \
                    int qpos = qpos0 + quad * 4 + r;                                    \
                    ev = (kpos > qpos) ? 0.f : ev;                                      \
                }                                                                       \
                e[r] = ev;                                                              \
            }                                                                           \
            unsigned pk01 = __builtin_bit_cast(unsigned,                                \
                                __builtin_amdgcn_cvt_pkrtz(e[0], e[1]));                \
            unsigned pk23 = __builtin_bit_cast(unsigned,                                \
                                __builtin_amdgcn_cvt_pkrtz(e[2], e[3]));                \
            int col = nt * 16 + l15;                                                    \
            Pw[(quad * 4 + 0) * 72 + col] = (unsigned short)pk01;                       \
            Pw[(quad * 4 + 1) * 72 + col] = (unsigned short)(pk01 >> 16);               \
            Pw[(quad * 4 + 2) * 72 + col] = (unsigned short)pk23;                       \
            Pw[(quad * 4 + 3) * 72 + col] = (unsigned short)(pk23 >> 16);               \
        }                                                                               \
        __asm__ volatile("s_waitcnt lgkmcnt(0)" ::: "memory");                          \
        f16x8 pf0 = *(const f16x8*)(Pw + l15 * 72 + quad * 8);                          \
        f16x8 pf1 = *(const f16x8*)(Pw + l15 * 72 + 32 + quad * 8);                     \
        lacc = MFMA_F16(pf0, ones, lacc);                                               \
        lacc = MFMA_F16(pf1, ones, lacc);                                               \
        _Pragma("unroll")                                                               \
        for (int nt = 0; nt < 4; ++nt) {                                                \
            int row = nt * 16 + l15;                                                    \
            int cof = (quad ^ (row & 7)) * 8;                                           \
            f16x8 vf0 = *(const f16x8*)(Vc + row * 64 + cof);                           \
            f16x8 vf1 = *(const f16x8*)(Vc + row * 64 + (cof ^ 32));                    \
            accO[nt] = MFMA_F16(pf0, vf0, accO[nt]);                                    \
            accO[nt] = MFMA_F16(pf1, vf1, accO[nt]);                                    \
        }                                                                               \
    }

__global__ __launch_bounds__(256) void flash_attn(const unsigned short* __restrict__ Q,
                                                  const unsigned short* __restrict__ Kb,
                                                  const unsigned short* __restrict__ Vt,
                                                  unsigned short* __restrict__ O) {
    int id = blockIdx.x;
    int xcd = id & 7;
    int sl = id >> 3;           // slot within XCD, [0,128)
    int rr = sl >> 5;           // assignment round 0..3
    int j  = sl & 31;           // CU-ish slot within XCD
    int qt;
    if (rr == 0)      qt = j;
    else if (rr == 1) qt = 31 - j;
    else if (rr == 2) qt = (j + 16) & 31;
    else              qt = 31 - ((j + 16) & 31);
    int bh = xcd + 8 * rr;      // 4 bh per XCD -> K/V stream L2-resident (2 MB/XCD)
    int b = bh >> 4, h = bh & 15;
    int tid = threadIdx.x, w = tid >> 6, lane = tid & 63;
    int quad = lane >> 4, l15 = lane & 15;
    int qrow0 = b * 2048 + qt * 64 + w * 16;
    int qpos0 = qt * 64 + w * 16;

    __shared__ unsigned short Ks[2][64 * 64];  // bf16 [key][d], chunk-swizzled
    __shared__ unsigned short Vs[2][64 * 64];  // f16  [d][key], chunk-swizzled
    __shared__ unsigned short Ps[4][16 * 72];  // f16 per-wave P scratch, stride 72

    bf16x8 qf0, qf1;
    {
        const unsigned short* qp = Q + (size_t)(qrow0 + l15) * 1024 + h * 64 + quad * 8;
        qf0 = *(const bf16x8*)qp;
        qf1 = *(const bf16x8*)(qp + 32);
    }
    f16x8 ones;
#pragma unroll
    for (int jj = 0; jj < 8; ++jj) ones[jj] = (_Float16)1.0f;

    // staging: chunk L=(w*2+i)*64+lane; row r=L>>3, lds col cpos=L&7 holds src cpos^(r&7)
    int L0 = w * 128 + lane;
    int L1 = L0 + 64;
    int r0 = L0 >> 3, c0s = (L0 & 7) ^ (r0 & 7);
    int r1 = L1 >> 3, c1s = (L1 & 7) ^ (r1 & 7);
    const unsigned short* Kg0 = Kb + (size_t)(b * 2048 + r0) * 1024 + h * 64 + c0s * 8;
    const unsigned short* Kg1 = Kb + (size_t)(b * 2048 + r1) * 1024 + h * 64 + c1s * 8;
    const unsigned short* Vg0 = Vt + (size_t)(h * 64 + r0) * 4096 + b * 2048 + c0s * 8;
    const unsigned short* Vg1 = Vt + (size_t)(h * 64 + r1) * 4096 + b * 2048 + c1s * 8;

    f32x4 accO[4];
#pragma unroll
    for (int nt = 0; nt < 4; ++nt) accO[nt] = f32x4{0.f, 0.f, 0.f, 0.f};
    f32x4 lacc = f32x4{0.f, 0.f, 0.f, 0.f};

    // prologue: stage key-block 0 into buf 0
    gl_lds16(Kg0, Ks[0] + L0 * 8);
    gl_lds16(Kg1, Ks[0] + L1 * 8);
    gl_lds16(Vg0, Vs[0] + L0 * 8);
    gl_lds16(Vg1, Vs[0] + L1 * 8);

    for (int kb = 0; kb < qt; ++kb) {      // fully-unmasked key blocks
        __syncthreads();                    // drains stage(kb), then barrier
        int bi = (kb + 1) & 1;
        size_t ko = (size_t)(kb + 1) * 64 * 1024;
        size_t vo = (size_t)(kb + 1) * 64;
        gl_lds16(Kg0 + ko, Ks[bi] + L0 * 8);
        gl_lds16(Kg1 + ko, Ks[bi] + L1 * 8);
        gl_lds16(Vg0 + vo, Vs[bi] + L0 * 8);
        gl_lds16(Vg1 + vo, Vs[bi] + L1 * 8);
        FBODY(kb, 0)
    }
    __syncthreads();
    FBODY(qt, 1)                            // diagonal block, masked

    // ---- epilogue: O / rowsum (lacc reg r = rowsum of q-row quad*4+r) ----
    float inv[4];
#pragma unroll
    for (int r = 0; r < 4; ++r) inv[r] = 1.0f / lacc[r];
#pragma unroll
    for (int nt = 0; nt < 4; ++nt)
#pragma unroll
        for (int r = 0; r < 4; ++r)
            O[(size_t)(qrow0 + quad * 4 + r) * 1024 + h * 64 + nt * 16 + l15] =
                f2bf(accO[nt][r] * inv[r]);
}

extern "C" void kernel_launch(void* const* d_in, const int* in_sizes, int n_in,
                              void* d_out, int out_size, void* d_ws, size_t ws_size,
                              hipStream_t stream) {
    (void)in_sizes; (void)n_in; (void)out_size; (void)ws_size;
    const float* x  = (const float*)d_in[0];
    const float* wq = (const float*)d_in[1];
    const float* wk = (const float*)d_in[2];
    const float* wv = (const float*)d_in[3];
    const float* wo = (const float*)d_in[4];
    float* out = (float*)d_out;

    const size_t T = (size_t)4096 * 1024;
    const size_t W = (size_t)1024 * 1024;
    unsigned short* Q   = (unsigned short*)d_ws;
    unsigned short* K   = Q + T;
    unsigned short* Vt  = K + T;      // f16 [ch][token], ldc 4096
    unsigned short* AO  = Vt + T;
    unsigned short* xb  = AO + T;
    unsigned short* wqb = xb + T;
    unsigned short* wkb = wqb + W;
    unsigned short* wvb = wkb + W;
    unsigned short* wob = wvb + W;

    cvt_all  <<<dim3(4096),   256, 0, stream>>>(x, wq, wk, wv, wo, xb, wqb, wkb, wvb, wob);
    gemm_qkv <<<dim3(32, 24), 256, 0, stream>>>(xb, wqb, wkb, wvb, Q, K, Vt);
    rope_qk  <<<dim3(16384),  256, 0, stream>>>(Q, K);
    flash_attn<<<dim3(1024),  256, 0, stream>>>(Q, K, Vt, AO);
    gemm_out <<<dim3(32, 8),  256, 0, stream>>>(AO, wob, out);
}

// Round 8
// 187.293 us; speedup vs baseline: 1.1089x; 1.0630x over previous
//
#include <hip/hip_runtime.h>

typedef __attribute__((ext_vector_type(8))) __bf16 bf16x8;
typedef __attribute__((ext_vector_type(8))) _Float16 f16x8;
typedef __attribute__((ext_vector_type(4))) float f32x4;
typedef __attribute__((ext_vector_type(8))) unsigned short u16x8;

#define MFMA_BF16(a, b, c) __builtin_amdgcn_mfma_f32_16x16x32_bf16((a), (b), (c), 0, 0, 0)
#define MFMA_F16(a, b, c)  __builtin_amdgcn_mfma_f32_16x16x32_f16((a), (b), (c), 0, 0, 0)
#define LOG2E 1.44269504088896340736f
#define QSCALE 0.18033688011112042f   // 0.125 * log2(e), folded into wq at cvt

__device__ __forceinline__ float b2f(unsigned short u) {
    union { unsigned int i; float f; } v; v.i = ((unsigned int)u) << 16; return v.f;
}
__device__ __forceinline__ unsigned short f2bf(float f) {
    union { float f; unsigned int i; } v; v.f = f;
    unsigned int u = v.i;
    return (unsigned short)((u + 0x7fffu + ((u >> 16) & 1u)) >> 16);
}

// async global->LDS, 16B/lane. HW dest = wave-uniform base + lane*16 (m104).
// Swizzle is applied on the GLOBAL side so conflict-free LDS layouts coexist with it.
__device__ __forceinline__ void gl_lds16(const void* g, void* l) {
    __builtin_amdgcn_global_load_lds(
        (const __attribute__((address_space(1))) void*)g,
        (__attribute__((address_space(3))) void*)l,
        16, 0, 0);
}

// ---------------- fp32 -> bf16 conversion of all 5 inputs; wq pre-scaled ----------
__global__ __launch_bounds__(256) void cvt_all(const float* __restrict__ x,
                                               const float* __restrict__ wq,
                                               const float* __restrict__ wk,
                                               const float* __restrict__ wv,
                                               const float* __restrict__ wo,
                                               unsigned short* __restrict__ xb,
                                               unsigned short* __restrict__ wqb,
                                               unsigned short* __restrict__ wkb,
                                               unsigned short* __restrict__ wvb,
                                               unsigned short* __restrict__ wob) {
    int id = blockIdx.x * 256 + threadIdx.x;  // [0, 1M)
    const float* src; unsigned short* dst; size_t off; float scl = 1.0f;
    if (id < 524288)      { src = x;  dst = xb;  off = (size_t)id * 8; }
    else if (id < 655360) { src = wq; dst = wqb; off = (size_t)(id - 524288) * 8; scl = QSCALE; }
    else if (id < 786432) { src = wk; dst = wkb; off = (size_t)(id - 655360) * 8; }
    else if (id < 917504) { src = wv; dst = wvb; off = (size_t)(id - 786432) * 8; }
    else                  { src = wo; dst = wob; off = (size_t)(id - 917504) * 8; }
    float4 a = *(const float4*)(src + off);
    float4 b = *(const float4*)(src + off + 4);
    u16x8 o;
    o[0] = f2bf(a.x * scl); o[1] = f2bf(a.y * scl); o[2] = f2bf(a.z * scl); o[3] = f2bf(a.w * scl);
    o[4] = f2bf(b.x * scl); o[5] = f2bf(b.y * scl); o[6] = f2bf(b.z * scl); o[7] = f2bf(b.w * scl);
    *(u16x8*)(dst + off) = o;
}

// ---------------- GEMM core: C[MxN] = A[MxK]*B[NxK]^T, bf16 in, fp32 accum --------
// 128x128 tile, BK=32, K=1024 fixed, A/B row stride 1024. LDS chunk (r,cpos) holds
// source chunk cpos^((r>>1)&3) -> frag ds_read_b128 is 2-way (free).
// MODE: 0 = bf16 out, 1 = f32 out, 2 = f16 out, 3 = bf16 out with fused RoPE
// (rows = tokens, cols = channels; pair partner via shfl_xor(1); scale pre-folded).
template <int MODE>
__device__ __forceinline__ void gemm128_bt(const unsigned short* __restrict__ A,
                                           const unsigned short* __restrict__ B,
                                           void* __restrict__ Cv,
                                           int m0, int n0, int ldc,
                                           unsigned short* As, unsigned short* Bs) {
    const int tid = threadIdx.x;
    const int w = tid >> 6, lane = tid & 63;
    const int quad = lane >> 4, l15 = lane & 15;
    const int wm = w & 1, wn = w >> 1;

    f32x4 acc[4][4];
#pragma unroll
    for (int mt = 0; mt < 4; ++mt)
#pragma unroll
        for (int nt = 0; nt < 4; ++nt) acc[mt][nt] = f32x4{0.f, 0.f, 0.f, 0.f};

    for (int k0 = 0; k0 < 1024; k0 += 32) {
        __syncthreads();
#pragma unroll
        for (int i = 0; i < 2; ++i) {
            int L = (w * 2 + i) * 64 + lane;      // chunk index in tile
            int r = L >> 2;
            int c = (L & 3) ^ ((r >> 1) & 3);     // swizzled source chunk
            gl_lds16(A + (size_t)(m0 + r) * 1024 + k0 + c * 8, As + L * 8);
            gl_lds16(B + (size_t)(n0 + r) * 1024 + k0 + c * 8, Bs + L * 8);
        }
        __syncthreads();

        bf16x8 af[4], bfr[4];
#pragma unroll
        for (int mt = 0; mt < 4; ++mt) {
            int row = wm * 64 + mt * 16 + l15;
            af[mt] = *(const bf16x8*)(As + row * 32 + (quad ^ ((row >> 1) & 3)) * 8);
        }
#pragma unroll
        for (int nt = 0; nt < 4; ++nt) {
            int row = wn * 64 + nt * 16 + l15;
            bfr[nt] = *(const bf16x8*)(Bs + row * 32 + (quad ^ ((row >> 1) & 3)) * 8);
        }
#pragma unroll
        for (int mt = 0; mt < 4; ++mt)
#pragma unroll
            for (int nt = 0; nt < 4; ++nt)
                acc[mt][nt] = MFMA_BF16(af[mt], bfr[nt], acc[mt][nt]);
    }

    // ---- fused RoPE (MODE 3): ch = nt*16+l15 (row-independent), pp = ch>>1 ----
    float invf[4], sgn = 0.f;
    if constexpr (MODE == 3) {
        sgn = (l15 & 1) ? 1.0f : -1.0f;   // odd lane: +p*sin ; even lane: -p*sin
#pragma unroll
        for (int nt = 0; nt < 4; ++nt)
            invf[nt] = exp2f(-0.41524101186092029f * (float)((nt * 16 + l15) >> 1));
    }

#pragma unroll
    for (int mt = 0; mt < 4; ++mt) {
        int grow = m0 + wm * 64 + mt * 16 + quad * 4;
#pragma unroll
        for (int nt = 0; nt < 4; ++nt) {
            int gcol = n0 + wn * 64 + nt * 16 + l15;
#pragma unroll
            for (int r = 0; r < 4; ++r) {
                float val = acc[mt][nt][r];
                size_t idx = (size_t)(grow + r) * ldc + gcol;
                if constexpr (MODE == 0) {
                    ((unsigned short*)Cv)[idx] = f2bf(val);
                } else if constexpr (MODE == 1) {
                    ((float*)Cv)[idx] = val;
                } else if constexpr (MODE == 2) {
                    _Float16 hv = (_Float16)val;
                    ((unsigned short*)Cv)[idx] = __builtin_bit_cast(unsigned short, hv);
                } else {
                    float p = __shfl_xor(val, 1);              // pair partner channel
                    float pos = (float)((grow + r) & 2047);    // seq position
                    float ang = pos * invf[nt];
                    float out = val * __cosf(ang) + sgn * p * __sinf(ang);
                    ((unsigned short*)Cv)[idx] = f2bf(out);
                }
            }
        }
    }
}

// Q/K: bf16 + fused RoPE (ldc 1024). V: C = Wv * X^T = V^T[ch][token] f16 (ldc 4096).
__global__ __launch_bounds__(256) void gemm_qkv(const unsigned short* __restrict__ X,
                                                const unsigned short* __restrict__ Wq,
                                                const unsigned short* __restrict__ Wk,
                                                const unsigned short* __restrict__ Wv,
                                                unsigned short* __restrict__ Qo,
                                                unsigned short* __restrict__ Ko,
                                                unsigned short* __restrict__ Vt) {
    __shared__ unsigned short As[128 * 32];
    __shared__ unsigned short Bs[128 * 32];
    int y = blockIdx.y;
    if (y < 16) {
        int sel = y >> 3;
        int m0 = blockIdx.x * 128;         // tokens
        int n0 = (y & 7) * 128;            // channels
        const unsigned short* B = sel ? Wk : Wq;
        unsigned short* C = sel ? Ko : Qo;
        gemm128_bt<3>(X, B, C, m0, n0, 1024, As, Bs);
    } else {
        int m0 = (y & 7) * 128;            // channels
        int n0 = blockIdx.x * 128;         // tokens
        gemm128_bt<2>(Wv, X, Vt, m0, n0, 4096, As, Bs);
    }
}

__global__ __launch_bounds__(256) void gemm_out(const unsigned short* __restrict__ A,
                                                const unsigned short* __restrict__ Wo,
                                                float* __restrict__ C) {
    __shared__ unsigned short As[128 * 32];
    __shared__ unsigned short Bs[128 * 32];
    gemm128_bt<1>(A, Wo, C, blockIdx.x * 128, blockIdx.y * 128, 1024, As, Bs);
}

// ---------------- Flash attention, causal, M=0, SINGLE-buffer K/V ------------------
// LDS 25.6KB -> 6 blocks/CU (24 waves/CU): occupancy hides the L2-hit load latency
// that the double buffer used to cover (K/V are L2-resident via the XCD bh map).
// Mask peeled to the diagonal key-block; rowsum via ones-MFMA.
#define FBODY(KB, MASKED)                                                               \
    {                                                                                   \
        const int kb_ = (KB);                                                           \
        f32x4 sc[4];                                                                    \
        _Pragma("unroll")                                                               \
        for (int nt = 0; nt < 4; ++nt) {                                                \
            int row = nt * 16 + l15;                                                    \
            int cof = (quad ^ (row & 7)) * 8;                                           \
            bf16x8 kf0 = *(const bf16x8*)(Ks + row * 64 + cof);                         \
            bf16x8 kf1 = *(const bf16x8*)(Ks + row * 64 + (cof ^ 32));                  \
            f32x4 z = f32x4{0.f, 0.f, 0.f, 0.f};                                        \
            sc[nt] = MFMA_BF16(qf0, kf0, z);                                            \
            sc[nt] = MFMA_BF16(qf1, kf1, sc[nt]);                                       \
        }                                                                               \
        unsigned short* Pw = Ps[w];                                                     \
        _Pragma("unroll")                                                               \
        for (int nt = 0; nt < 4; ++nt) {                                                \
            float e[4];                                                                 \
            _Pragma("unroll")                                                           \
            for (int r = 0; r < 4; ++r) {                                               \
                float ev = exp2f(sc[nt][r]);                                            \
                if (MASKED) {                                                           \
                    int kpos = kb_ * 64 + nt * 16 + l15;                                \
                    int qpos = qpos0 + quad * 4 + r;                                    \
                    ev = (kpos > qpos) ? 0.f : ev;                                      \
                }                                                                       \
                e[r] = ev;                                                              \
            }                                                                           \
            unsigned pk01 = __builtin_bit_cast(unsigned,                                \
                                __builtin_amdgcn_cvt_pkrtz(e[0], e[1]));                \
            unsigned pk23 = __builtin_bit_cast(unsigned,                                \
                                __builtin_amdgcn_cvt_pkrtz(e[2], e[3]));                \
            int col = nt * 16 + l15;                                                    \
            Pw[(quad * 4 + 0) * 72 + col] = (unsigned short)pk01;                       \
            Pw[(quad * 4 + 1) * 72 + col] = (unsigned short)(pk01 >> 16);               \
            Pw[(quad * 4 + 2) * 72 + col] = (unsigned short)pk23;                       \
            Pw[(quad * 4 + 3) * 72 + col] = (unsigned short)(pk23 >> 16);               \
        }                                                                               \
        __asm__ volatile("s_waitcnt lgkmcnt(0)" ::: "memory");                          \
        f16x8 pf0 = *(const f16x8*)(Pw + l15 * 72 + quad * 8);                          \
        f16x8 pf1 = *(const f16x8*)(Pw + l15 * 72 + 32 + quad * 8);                     \
        lacc = MFMA_F16(pf0, ones, lacc);                                               \
        lacc = MFMA_F16(pf1, ones, lacc);                                               \
        _Pragma("unroll")                                                               \
        for (int nt = 0; nt < 4; ++nt) {                                                \
            int row = nt * 16 + l15;                                                    \
            int cof = (quad ^ (row & 7)) * 8;                                           \
            f16x8 vf0 = *(const f16x8*)(Vs + row * 64 + cof);                           \
            f16x8 vf1 = *(const f16x8*)(Vs + row * 64 + (cof ^ 32));                    \
            accO[nt] = MFMA_F16(pf0, vf0, accO[nt]);                                    \
            accO[nt] = MFMA_F16(pf1, vf1, accO[nt]);                                    \
        }                                                                               \
    }

__global__ __launch_bounds__(256) void flash_attn(const unsigned short* __restrict__ Q,
                                                  const unsigned short* __restrict__ Kb,
                                                  const unsigned short* __restrict__ Vt,
                                                  unsigned short* __restrict__ O) {
    int id = blockIdx.x;
    int xcd = id & 7;
    int sl = id >> 3;           // slot within XCD, [0,128)
    int rr = sl >> 5;           // 0..3
    int j  = sl & 31;
    int qt;
    if (rr == 0)      qt = j;
    else if (rr == 1) qt = 31 - j;
    else if (rr == 2) qt = (j + 16) & 31;
    else              qt = 31 - ((j + 16) & 31);
    int bh = xcd + 8 * rr;      // 4 bh per XCD -> K/V stream L2-resident (2 MB/XCD)
    int b = bh >> 4, h = bh & 15;
    int tid = threadIdx.x, w = tid >> 6, lane = tid & 63;
    int quad = lane >> 4, l15 = lane & 15;
    int qrow0 = b * 2048 + qt * 64 + w * 16;
    int qpos0 = qt * 64 + w * 16;

    __shared__ unsigned short Ks[64 * 64];     // bf16 [key][d], chunk-swizzled
    __shared__ unsigned short Vs[64 * 64];     // f16  [d][key], chunk-swizzled
    __shared__ unsigned short Ps[4][16 * 72];  // f16 per-wave P scratch, stride 72

    bf16x8 qf0, qf1;
    {
        const unsigned short* qp = Q + (size_t)(qrow0 + l15) * 1024 + h * 64 + quad * 8;
        qf0 = *(const bf16x8*)qp;
        qf1 = *(const bf16x8*)(qp + 32);
    }
    f16x8 ones;
#pragma unroll
    for (int jj = 0; jj < 8; ++jj) ones[jj] = (_Float16)1.0f;

    // staging: chunk L=(w*2+i)*64+lane; row r=L>>3, lds col cpos=L&7 holds src cpos^(r&7)
    int L0 = w * 128 + lane;
    int L1 = L0 + 64;
    int r0 = L0 >> 3, c0s = (L0 & 7) ^ (r0 & 7);
    int r1 = L1 >> 3, c1s = (L1 & 7) ^ (r1 & 7);
    const unsigned short* Kg0 = Kb + (size_t)(b * 2048 + r0) * 1024 + h * 64 + c0s * 8;
    const unsigned short* Kg1 = Kb + (size_t)(b * 2048 + r1) * 1024 + h * 64 + c1s * 8;
    const unsigned short* Vg0 = Vt + (size_t)(h * 64 + r0) * 4096 + b * 2048 + c0s * 8;
    const unsigned short* Vg1 = Vt + (size_t)(h * 64 + r1) * 4096 + b * 2048 + c1s * 8;

    f32x4 accO[4];
#pragma unroll
    for (int nt = 0; nt < 4; ++nt) accO[nt] = f32x4{0.f, 0.f, 0.f, 0.f};
    f32x4 lacc = f32x4{0.f, 0.f, 0.f, 0.f};

    for (int kb = 0; kb <= qt; ++kb) {
        __syncthreads();                     // previous compute done before restage
        {
            size_t ko = (size_t)kb * 64 * 1024;
            size_t vo = (size_t)kb * 64;
            gl_lds16(Kg0 + ko, Ks + L0 * 8);
            gl_lds16(Kg1 + ko, Ks + L1 * 8);
            gl_lds16(Vg0 + vo, Vs + L0 * 8);
            gl_lds16(Vg1 + vo, Vs + L1 * 8);
        }
        __syncthreads();                     // vmcnt drain + visibility
        if (kb < qt) {
            FBODY(kb, 0)
        } else {
            FBODY(kb, 1)
        }
    }

    // ---- epilogue: O / rowsum (lacc reg r = rowsum of q-row quad*4+r) ----
    float inv[4];
#pragma unroll
    for (int r = 0; r < 4; ++r) inv[r] = 1.0f / lacc[r];
#pragma unroll
    for (int nt = 0; nt < 4; ++nt)
#pragma unroll
        for (int r = 0; r < 4; ++r)
            O[(size_t)(qrow0 + quad * 4 + r) * 1024 + h * 64 + nt * 16 + l15] =
                f2bf(accO[nt][r] * inv[r]);
}

extern "C" void kernel_launch(void* const* d_in, const int* in_sizes, int n_in,
                              void* d_out, int out_size, void* d_ws, size_t ws_size,
                              hipStream_t stream) {
    (void)in_sizes; (void)n_in; (void)out_size; (void)ws_size;
    const float* x  = (const float*)d_in[0];
    const float* wq = (const float*)d_in[1];
    const float* wk = (const float*)d_in[2];
    const float* wv = (const float*)d_in[3];
    const float* wo = (const float*)d_in[4];
    float* out = (float*)d_out;

    const size_t T = (size_t)4096 * 1024;
    const size_t W = (size_t)1024 * 1024;
    unsigned short* Q   = (unsigned short*)d_ws;
    unsigned short* K   = Q + T;
    unsigned short* Vt  = K + T;      // f16 [ch][token], ldc 4096
    unsigned short* xb  = Vt + T;
    unsigned short* AO  = xb;         // alias: xb dead after gemm_qkv, AO written by flash
    unsigned short* wqb = xb + T;
    unsigned short* wkb = wqb + W;
    unsigned short* wvb = wkb + W;
    unsigned short* wob = wvb + W;
    // ws use: 4*8MB + 4*2MB = 40MB

    cvt_all  <<<dim3(4096),   256, 0, stream>>>(x, wq, wk, wv, wo, xb, wqb, wkb, wvb, wob);
    gemm_qkv <<<dim3(32, 24), 256, 0, stream>>>(xb, wqb, wkb, wvb, Q, K, Vt);
    flash_attn<<<dim3(1024),  256, 0, stream>>>(Q, K, Vt, AO);
    gemm_out <<<dim3(32, 8),  256, 0, stream>>>(AO, wob, out);
}